// Round 1
// baseline (49.162 us; speedup 1.0000x reference)
//
#include <hip/hip_runtime.h>
#include <math.h>

#define N 1024
#define NN (N * N)
#define MLP_IN 3137
#define EPS 1e-5f
#define NB_PAIR 512

// ws float offsets
#define WS_D2MAX 0 // uint bits
#define WS_D2MIN 1 // uint bits
#define WS_A 2     // 4 floats
#define WS_STOT 6
#define WS_PART 16 // NB_PAIR*8 floats
#define WS_Z0 4608
#define WS_Z1 4864
#define WS_Z2 5120
#define WS_Z3 5376

__device__ __forceinline__ float gelu_tanh(float v) {
    float u = 0.7978845608028654f * (v + 0.044715f * v * v * v);
    return 0.5f * v * (1.0f + tanhf(u));
}

// 1 block x 256 threads: q = Wq*t + bq; A_h = sum_d Wk[h*64+d]*q[h*64+d]; init max/min slots
__global__ void vf_init(const float* __restrict__ t, const float* __restrict__ Wq,
                        const float* __restrict__ bq, const float* __restrict__ Wk,
                        float* __restrict__ wsf) {
    int i = threadIdx.x;
    float q = Wq[i] * t[0] + bq[i];
    float prod = Wk[i] * q;
    for (int off = 32; off; off >>= 1) prod += __shfl_down(prod, off);
    if ((i & 63) == 0) wsf[WS_A + (i >> 6)] = prod;
    if (i == 0) {
        unsigned* u = (unsigned*)wsf;
        u[WS_D2MAX] = 0u;
        u[WS_D2MIN] = 0x7f800000u; // +inf
    }
}

// global d^2 max/min over ordered pairs (uint-bit atomics: exact, deterministic)
__global__ void vf_pass1(const float* __restrict__ x, float* __restrict__ wsf) {
    __shared__ float xs[3072];
    for (int i = threadIdx.x; i < 3072; i += blockDim.x) xs[i] = x[i];
    __syncthreads();
    float lmax = 0.f, lmin = INFINITY;
    int stride = gridDim.x * blockDim.x;
    for (int idx = blockIdx.x * blockDim.x + threadIdx.x; idx < NN; idx += stride) {
        int i = idx >> 10, j = idx & (N - 1);
        if (i == j) continue;
        float dx = xs[3 * i] - xs[3 * j];
        float dy = xs[3 * i + 1] - xs[3 * j + 1];
        float dz = xs[3 * i + 2] - xs[3 * j + 2];
        float d2 = dx * dx + dy * dy + dz * dz;
        lmax = fmaxf(lmax, d2);
        lmin = fminf(lmin, d2);
    }
    for (int off = 32; off; off >>= 1) {
        lmax = fmaxf(lmax, __shfl_down(lmax, off));
        lmin = fminf(lmin, __shfl_down(lmin, off));
    }
    __shared__ float smax[4], smin[4];
    int wid = threadIdx.x >> 6;
    if ((threadIdx.x & 63) == 0) { smax[wid] = lmax; smin[wid] = lmin; }
    __syncthreads();
    if (threadIdx.x == 0) {
        float m = smax[0], n = smin[0];
        for (int w = 1; w < 4; w++) { m = fmaxf(m, smax[w]); n = fminf(n, smin[w]); }
        atomicMax((unsigned*)wsf + WS_D2MAX, __float_as_uint(m));
        atomicMin((unsigned*)wsf + WS_D2MIN, __float_as_uint(n));
    }
}

// per-head sum exp(A*d - m) and sum d*exp(...) -> deterministic per-block partials
__global__ void vf_pass2(const float* __restrict__ x, float* __restrict__ wsf) {
    __shared__ float xs[3072];
    for (int i = threadIdx.x; i < 3072; i += blockDim.x) xs[i] = x[i];
    __syncthreads();
    unsigned* u = (unsigned*)wsf;
    float dmax = sqrtf(__uint_as_float(u[WS_D2MAX]));
    float dmin = sqrtf(__uint_as_float(u[WS_D2MIN]));
    float A[4], m[4];
    for (int h = 0; h < 4; h++) {
        A[h] = wsf[WS_A + h];
        m[h] = (A[h] >= 0.f) ? A[h] * dmax : A[h] * dmin;
    }
    float se[4] = {0.f, 0.f, 0.f, 0.f}, sd[4] = {0.f, 0.f, 0.f, 0.f};
    int stride = gridDim.x * blockDim.x;
    for (int idx = blockIdx.x * blockDim.x + threadIdx.x; idx < NN; idx += stride) {
        int i = idx >> 10, j = idx & (N - 1);
        if (i == j) continue;
        float dx = xs[3 * i] - xs[3 * j];
        float dy = xs[3 * i + 1] - xs[3 * j + 1];
        float dz = xs[3 * i + 2] - xs[3 * j + 2];
        float d = sqrtf(dx * dx + dy * dy + dz * dz);
        for (int h = 0; h < 4; h++) {
            float e = __expf(A[h] * d - m[h]);
            se[h] += e;
            sd[h] += d * e;
        }
    }
    for (int off = 32; off; off >>= 1) {
        for (int h = 0; h < 4; h++) {
            se[h] += __shfl_down(se[h], off);
            sd[h] += __shfl_down(sd[h], off);
        }
    }
    __shared__ float red[4][8];
    int wid = threadIdx.x >> 6;
    if ((threadIdx.x & 63) == 0)
        for (int h = 0; h < 4; h++) { red[wid][h] = se[h]; red[wid][4 + h] = sd[h]; }
    __syncthreads();
    if (threadIdx.x < 8) {
        float s = red[0][threadIdx.x] + red[1][threadIdx.x] + red[2][threadIdx.x] + red[3][threadIdx.x];
        wsf[WS_PART + blockIdx.x * 8 + threadIdx.x] = s;
    }
}

// reduce NB_PAIR partials -> s_total = sum_h sd_h/se_h
__global__ void vf_finalize(float* __restrict__ wsf) {
    float local[8];
    for (int k = 0; k < 8; k++) local[k] = 0.f;
    for (int b = threadIdx.x; b < NB_PAIR; b += blockDim.x)
        for (int k = 0; k < 8; k++) local[k] += wsf[WS_PART + b * 8 + k];
    for (int off = 32; off; off >>= 1)
        for (int k = 0; k < 8; k++) local[k] += __shfl_down(local[k], off);
    __shared__ float red[4][8];
    int wid = threadIdx.x >> 6;
    if ((threadIdx.x & 63) == 0)
        for (int k = 0; k < 8; k++) red[wid][k] = local[k];
    __syncthreads();
    if (threadIdx.x == 0) {
        float s = 0.f;
        for (int h = 0; h < 4; h++) {
            float seh = red[0][h] + red[1][h] + red[2][h] + red[3][h];
            float sdh = red[0][4 + h] + red[1][4 + h] + red[2][4 + h] + red[3][4 + h];
            s += sdh / seh;
        }
        wsf[WS_STOT] = s;
    }
}

// z0[o] = dot(W0[o,:], feats) + b0[o];  feats = [x, s_tot*Wv+4*bv, t]
__global__ void vf_layer0(const float* __restrict__ x, const float* __restrict__ t,
                          const float* __restrict__ Wv, const float* __restrict__ bv,
                          const float* __restrict__ W0, const float* __restrict__ b0,
                          float* __restrict__ wsf) {
    int o = blockIdx.x;
    float st = wsf[WS_STOT];
    const float* row = W0 + (long)o * MLP_IN;
    float acc = 0.f;
    for (int c = threadIdx.x; c < MLP_IN; c += 256) {
        float f;
        if (c < 3072) f = x[c];
        else if (c < 3136) f = st * Wv[c - 3072] + 4.0f * bv[c - 3072];
        else f = t[0];
        acc += row[c] * f;
    }
    for (int off = 32; off; off >>= 1) acc += __shfl_down(acc, off);
    __shared__ float red[4];
    if ((threadIdx.x & 63) == 0) red[threadIdx.x >> 6] = acc;
    __syncthreads();
    if (threadIdx.x == 0)
        wsf[WS_Z0 + o] = red[0] + red[1] + red[2] + red[3] + b0[o];
}

// zout[o] = dot(W[o,:], gelu(rmsnorm(zin)*gw)) + b[o]   (one wave per output row)
__global__ void vf_mlp(const float* __restrict__ zin, const float* __restrict__ W,
                       const float* __restrict__ b, const float* __restrict__ gw,
                       float* __restrict__ zout) {
    int o = blockIdx.x;
    int tid = threadIdx.x; // 64
    float zv[4];
    float ss = 0.f;
    for (int k = 0; k < 4; k++) {
        zv[k] = zin[tid + 64 * k];
        ss += zv[k] * zv[k];
    }
    for (int off = 32; off; off >>= 1) ss += __shfl_xor(ss, off);
    float rn = rsqrtf(ss * (1.0f / 256.0f) + EPS);
    const float* row = W + o * 256;
    float acc = 0.f;
    for (int k = 0; k < 4; k++) {
        int c = tid + 64 * k;
        float hc = gelu_tanh(zv[k] * rn * gw[c]);
        acc += row[c] * hc;
    }
    for (int off = 32; off; off >>= 1) acc += __shfl_down(acc, off);
    if (tid == 0) zout[o] = acc + b[o];
}

extern "C" void kernel_launch(void* const* d_in, const int* in_sizes, int n_in,
                              void* d_out, int out_size, void* d_ws, size_t ws_size,
                              hipStream_t stream) {
    const float* x = (const float*)d_in[0];
    const float* t = (const float*)d_in[1];
    const float* Wk = (const float*)d_in[2];
    // d_in[3] = bk: cancels in softmax, unused
    const float* Wv = (const float*)d_in[4];
    const float* bv = (const float*)d_in[5];
    const float* Wq = (const float*)d_in[6];
    const float* bq = (const float*)d_in[7];
    const float* W0 = (const float*)d_in[8];
    const float* b0 = (const float*)d_in[9];
    const float* Wh = (const float*)d_in[10];
    const float* bh = (const float*)d_in[11];
    const float* Wout = (const float*)d_in[12];
    const float* bout = (const float*)d_in[13];
    const float* g = (const float*)d_in[14];
    float* out = (float*)d_out;
    float* wsf = (float*)d_ws;

    vf_init<<<1, 256, 0, stream>>>(t, Wq, bq, Wk, wsf);
    vf_pass1<<<NB_PAIR, 256, 0, stream>>>(x, wsf);
    vf_pass2<<<NB_PAIR, 256, 0, stream>>>(x, wsf);
    vf_finalize<<<1, 256, 0, stream>>>(wsf);
    vf_layer0<<<256, 256, 0, stream>>>(x, t, Wv, bv, W0, b0, wsf);
    vf_mlp<<<256, 64, 0, stream>>>(wsf + WS_Z0, Wh, bh, g, wsf + WS_Z1);
    vf_mlp<<<256, 64, 0, stream>>>(wsf + WS_Z1, Wh + 65536, bh + 256, g + 256, wsf + WS_Z2);
    vf_mlp<<<256, 64, 0, stream>>>(wsf + WS_Z2, Wh + 131072, bh + 512, g + 512, wsf + WS_Z3);
    vf_mlp<<<3072, 64, 0, stream>>>(wsf + WS_Z3, Wout, bout, g + 768, out);
}